// Round 12
// baseline (2807.512 us; speedup 1.0000x reference)
//
#include <hip/hip_runtime.h>
#include <hip/hip_fp16.h>

// Problem constants
#define L_SEQ 576
#define BATCH 16
#define HIDDEN 800
#define NT 200      // N tiles per direction (3200/16)
#define KQ_HH 25    // K chunks for W_hh (800/32)
#define KQ_L1 50    // 1600/32
#define KQ_L0 2     // padded 64/32

typedef _Float16 h8 __attribute__((ext_vector_type(8)));
typedef _Float16 h4 __attribute__((ext_vector_type(4)));
typedef float f4 __attribute__((ext_vector_type(4)));
typedef int v4i __attribute__((ext_vector_type(4)));
typedef int v2i __attribute__((ext_vector_type(2)));

__device__ __forceinline__ float sigmoidf_(float x){
  x = fminf(30.f, fmaxf(-30.f, x));
  return 1.f/(1.f+__expf(-x));
}
__device__ __forceinline__ float tanhf_(float x){
  x = fminf(15.f, fmaxf(-15.f, x));
  float e = __expf(2.f*x);
  return (e-1.f)/(e+1.f);
}

// ---------------- init: fill h0+h1 with f16 sentinel (bit14 set) ------------
// Real h outputs satisfy |h|<1 -> f16 bit14 == 0. Sentinel 0x7C00 has bit14=1.
__global__ void init_h(v4i* __restrict__ h){
  size_t i = (size_t)blockIdx.x*256 + threadIdx.x;
  v4i s = {0x7C007C00, 0x7C007C00, 0x7C007C00, 0x7C007C00};
  h[i] = s;
}

// ---------------- build x (L*B, 64) f16: [onehot(20) | pssm(21) | pad0] -----
__global__ void build_x(const int* __restrict__ seq, const float* __restrict__ pssm,
                        _Float16* __restrict__ x){
  int i = blockIdx.x*256 + threadIdx.x;
  if(i >= L_SEQ*BATCH*64) return;
  int m = i >> 6, k = i & 63;
  float v = 0.f;
  if(k < 20)      v = (seq[m]==k) ? 1.f : 0.f;
  else if(k < 41) v = pssm[m*21 + (k-20)];
  x[i] = (_Float16)v;
}

// ---------------- weight prep: fp32 -> f16 MFMA fragment layout --------------
// Fragments consumed as the A-operand (W on the M-side) of the transposed
// MFMA. A-frag(M) and B-frag(M^T) are byte-identical on mfma_f32_16x16x32_f16
// (lane l -> primary dim l&15, k-run (l>>4)*8+j) -- unchanged from the
// validated round-2 version.
__global__ void prep_w(
  const float* __restrict__ whh0f, const float* __restrict__ whh0b,
  const float* __restrict__ whh1f, const float* __restrict__ whh1b,
  const float* __restrict__ wih1f, const float* __restrict__ wih1b,
  const float* __restrict__ wih0f, const float* __restrict__ wih0b,
  h8* __restrict__ wp_hh, h8* __restrict__ wp1, h8* __restrict__ wp0)
{
  long idx = (long)blockIdx.x*256 + threadIdx.x;
  const long J1 = 4L*320000, J2 = 2L*640000, J3 = 2L*25600;
  if(idx < J1){
    int d = (int)(idx/320000); int r = (int)(idx%320000);
    int T = r/1600, q = (r%1600)/64, l = r&63;
    const float* W = (d==0)?whh0f:(d==1)?whh0b:(d==2)?whh1f:whh1b;
    int c = l&15; int n = (c&3)*800 + T*4 + (c>>2);
    const float* src = W + (size_t)n*800 + q*32 + ((l>>4)<<3);
    h8 v;
    #pragma unroll
    for(int j=0;j<8;++j) v[j] = (_Float16)src[j];
    wp_hh[idx] = v;
  } else if(idx < J1+J2){
    long i2 = idx - J1;
    int d = (int)(i2/640000); int r = (int)(i2%640000);
    int T = r/3200, q = (r%3200)/64, l = r&63;
    const float* W = d ? wih1b : wih1f;
    int c = l&15; int n = (c&3)*800 + T*4 + (c>>2);
    const float* src = W + (size_t)n*1600 + q*32 + ((l>>4)<<3);
    h8 v;
    #pragma unroll
    for(int j=0;j<8;++j) v[j] = (_Float16)src[j];
    wp1[i2] = v;
  } else if(idx < J1+J2+J3){
    long i3 = idx - J1 - J2;
    int d = (int)(i3/25600); int r = (int)(i3%25600);
    int T = r/128, q = (r%128)/64, l = r&63;
    const float* W = d ? wih0b : wih0f;
    int c = l&15; int n = (c&3)*800 + T*4 + (c>>2);
    int k0 = q*32 + ((l>>4)<<3);
    h8 v;
    #pragma unroll
    for(int j=0;j<8;++j){ int k = k0+j; v[j] = (_Float16)((k<41)? W[(size_t)n*41+k] : 0.f); }
    wp0[i3] = v;
  }
}

// ------------- layer-0 input projection, TRANSPOSED (gates^T = W @ x^T) -----
__global__ __launch_bounds__(256) void gemm_l0(
  const _Float16* __restrict__ A,
  const h8* __restrict__ WpF, const h8* __restrict__ WpB,
  const float* __restrict__ bihF, const float* __restrict__ bhhF,
  const float* __restrict__ bihB, const float* __restrict__ bhhB,
  _Float16* __restrict__ GpF, _Float16* __restrict__ GpB)
{
  const int wv = threadIdx.x >> 6;
  const int l  = threadIdx.x & 63;
  const int mg = blockIdx.x % 144;
  const int tg = blockIdx.x / 144;       // 0..99
  const int mt = mg*4 + wv;              // 0..575 (timestep)
  const int dir = tg / 50;
  const int Tb  = (tg % 50) * 4;
  const h8* Wp = dir ? WpB : WpF;
  const float* bih = dir ? bihB : bihF;
  const float* bhh = dir ? bhhB : bhhF;
  _Float16* Gp = dir ? GpB : GpF;

  const _Float16* ab = A + (size_t)(mt*16 + (l&15))*64 + ((l>>4)<<3);
  f4 acc[4] = {{0.f,0.f,0.f,0.f},{0.f,0.f,0.f,0.f},{0.f,0.f,0.f,0.f},{0.f,0.f,0.f,0.f}};
  for(int q=0;q<KQ_L0;++q){
    h8 av = *(const h8*)(ab + q*32);
    #pragma unroll
    for(int j=0;j<4;++j){
      h8 bv = Wp[((size_t)(Tb+j)*KQ_L0 + q)*64 + l];
      acc[j] = __builtin_amdgcn_mfma_f32_16x16x32_f16(bv, av, acc[j], 0, 0, 0);
    }
  }
  const int hi = l >> 4;
  #pragma unroll
  for(int j=0;j<4;++j){
    int T = Tb + j;
    int u = T*4 + hi;
    h4 o;
    #pragma unroll
    for(int r=0;r<4;++r){
      float bias = bih[r*800+u] + bhh[r*800+u];
      o[r] = (_Float16)(acc[j][r] + bias);
    }
    *(h4*)(Gp + (((size_t)mt*NT + T)*64 + l)*4) = o;
  }
}

// ------------- layer-1 input projection, TRANSPOSED --------------------------
// ROUND-11 XCD-AFFINITY SWIZZLE. Round-11 measured gemm_l1 at 392us =
// 2.21GB / 5.6TB/s -- pinned at the fabric service ceiling (traffic model
// validated twice). A (h0 rows, 1.47GB of the 2.21) is re-read by the 50
// blocks sharing an mg; one mg's A-set is 819KB and fits a 4MB XCD L2.
// Swizzle blockIdx so all 50 blocks of an mg land on ONE XCD (bid%8 residue)
// and dispatch as a contiguous burst: A then comes from XCD-L2, fabric
// carries mostly W (0.74GB -> ~130us floor). Decode: cls=bid%8, j=bid/8,
// mg=(j/50)*8+cls, tgd=j%50; grid 2000 with mg>=36 early-exit. Worst case
// (mapping wrong for this chip): traffic unchanged, no regression.
// Tile unchanged from validated round-10: M_b=16, T_b=8, 512 thr, 2mt/wave,
// acc[2][8]=64 VGPR (~120 tot, 2 blocks/CU), W dbuf + 1-deep A prefetch.
__global__ __launch_bounds__(512) void gemm_l1(
  const h8* __restrict__ Af,
  const h8* __restrict__ WpF, const h8* __restrict__ WpB,
  const float* __restrict__ bihF, const float* __restrict__ bhhF,
  const float* __restrict__ bihB, const float* __restrict__ bhhB,
  _Float16* __restrict__ GpF, _Float16* __restrict__ GpB)
{
  __shared__ v4i ldsW[2][512];          // [buf][j*64+l] : 8 T x 64 lanes = 16KB
  const int tid = threadIdx.x;
  const int wv = tid >> 6;               // 0..7
  const int l  = tid & 63;
  // XCD-affinity decode (see header comment)
  const int bid = blockIdx.x;
  const int cls = bid & 7;
  const int j_  = bid >> 3;              // 0..249
  const int mg  = (j_/50)*8 + cls;       // 0..39 (>=36 invalid)
  const int tgd = j_ % 50;               // 0..49
  if(mg >= 36) return;
  const int dir = tgd / 25;
  const int tg  = tgd % 25;
  const int Tb  = tg * 8;                // 8 T per block
  const int mt0 = mg*16 + wv*2;          // 2 mt per wave
  const h8* Wp = dir ? WpB : WpF;
  const float* bih = dir ? bihB : bihF;
  const float* bhh = dir ? bhhB : bhhF;
  _Float16* Gp = dir ? GpB : GpF;

  const h8* a0 = Af + (size_t)(mt0+0)*3200 + l;
  const h8* a1 = Af + (size_t)(mt0+1)*3200 + l;

  f4 acc[2][8];
  #pragma unroll
  for(int m=0;m<2;++m)
    #pragma unroll
    for(int j=0;j<8;++j){ acc[m][j][0]=0.f; acc[m][j][1]=0.f; acc[m][j][2]=0.f; acc[m][j][3]=0.f; }

  // stage q=0 W (thread tid stages 16B: tile j=tid>>6, lane ll=tid&63)
  {
    int j = tid >> 6, ll = tid & 63;
    ldsW[0][tid] = *(const v4i*)(Wp + ((size_t)(Tb+j)*KQ_L1 + 0)*64 + ll);
  }
  // preload A q=0
  h8 av0 = a0[0], av1 = a1[0];
  __syncthreads();
  for(int q=0;q<KQ_L1;++q){
    const int buf = q & 1;
    const int qn = (q+1 < KQ_L1) ? q+1 : q;   // clamp: last iter re-loads q (unused)
    if(q+1 < KQ_L1){
      int j = tid >> 6, ll = tid & 63;
      ldsW[buf^1][tid] = *(const v4i*)(Wp + ((size_t)(Tb+j)*KQ_L1 + (q+1))*64 + ll);
    }
    // A prefetch for next iteration
    h8 an0 = a0[qn*64], an1 = a1[qn*64];
    #pragma unroll
    for(int j=0;j<8;++j){
      h8 bv = __builtin_bit_cast(h8, ldsW[buf][j*64 + l]);
      acc[0][j] = __builtin_amdgcn_mfma_f32_16x16x32_f16(bv, av0, acc[0][j], 0, 0, 0);
      acc[1][j] = __builtin_amdgcn_mfma_f32_16x16x32_f16(bv, av1, acc[1][j], 0, 0, 0);
    }
    __syncthreads();
    av0 = an0; av1 = an1;
  }
  const int hi = l >> 4;
  #pragma unroll
  for(int j=0;j<8;++j){
    int T = Tb + j;
    int u = T*4 + hi;
    float b0 = bih[0*800+u] + bhh[0*800+u];
    float b1 = bih[1*800+u] + bhh[1*800+u];
    float b2 = bih[2*800+u] + bhh[2*800+u];
    float b3 = bih[3*800+u] + bhh[3*800+u];
    #pragma unroll
    for(int m=0;m<2;++m){
      h4 o;
      o[0]=(_Float16)(acc[m][j][0]+b0); o[1]=(_Float16)(acc[m][j][1]+b1);
      o[2]=(_Float16)(acc[m][j][2]+b2); o[3]=(_Float16)(acc[m][j][3]+b3);
      *(h4*)(Gp + (((size_t)(mt0+m)*NT + T)*64 + l)*4) = o;
    }
  }
}

// ---------------- persistent LSTM layer (sentinel-sync, flag-free) -----------
// ROUND-6 WINNER, verbatim (1061-1085us/dispatch, re-confirmed rounds 9-11).
// DO NOT re-attempt: (a) bottom-of-loop pipelined sweep issue (round-3 raced
// on HW: hang + absmax corruption); (b) 2-tiles-per-wave consolidation
// (round-7, +27% regression).
// 100 blocks x 256 threads: 400 waves, one gate tile each. Blocks 0..49 fwd,
// 50..99 bwd.
// TRANSPOSED recurrence (round-5): gates^T = W_hh @ h^T; C: lane l, reg r =
// gate r (i,f,g,o) of (unit T*4+(l>>4), batch l&15); no gate shuffles, 1x
// activations, 2-shfl_xor store pack (one contiguous 128B burst per wave).
// Producers: 16 x 8B sc1 stores, then move on. Consumers: each of the 4 waves
// polls 7 of the 25 chunks (base wv*6) with sc1 loads, mirrors clean chunks
// to LDS, barrier, all waves ds_read all 25. LDS double-buffered on (s&1).
// CRITICAL: the s_waitcnt asm takes all polled w[] as "+v" operands so the
// sentinel check is data-dependent on the waitcnt.
__global__ __launch_bounds__(256,1) void lstm_kernel(
  const h8* __restrict__ WpF, const h8* __restrict__ WpB,
  const _Float16* __restrict__ GpF, const _Float16* __restrict__ GpB,
  h8* __restrict__ hfrag)
{
  __shared__ __attribute__((aligned(16))) char lds_h[2*25600];
  const int tid = threadIdx.x;
  const int wv  = tid >> 6;
  const int l   = tid & 63;
  const bool bwd = blockIdx.x >= 50;
  const int T = ((bwd ? (int)blockIdx.x - 50 : (int)blockIdx.x) << 2) + wv;  // 0..199
  const h8* Wp = bwd ? WpB : WpF;
  const _Float16* Gp = bwd ? GpB : GpF;
  const int dirOff = bwd ? 1600 : 0;     // h8 units

  h8 Bf[KQ_HH];
  #pragma unroll
  for(int q=0;q<KQ_HH;++q) Bf[q] = Wp[(T*KQ_HH + q)*64 + l];

  float cs = 0.f;                        // one cell per lane
  const int qb = wv*6;                   // this wave's poll base chunk
  const int storeUnit = ((T>>3)<<6) + (((T>>1)&3)<<4);  // h8-unit offset (+b)
  const int storeHalf = (T&1)<<3;                        // byte offset

  for(int s=0; s<L_SEQ; ++s){
    const int t = bwd ? (L_SEQ-1-s) : s;

    // prefetch Gp[t] (plain cached): 4 gates of this lane's cell
    h4 gp4 = *(const h4*)(Gp + (((size_t)t*NT + T)*64 + l)*4);

    #pragma unroll
    for(int q=0;q<KQ_HH;++q) asm volatile("" : "+v"(Bf[q]));   // keep resident

    char* lbuf = lds_h + (s&1)*25600;
    if(s > 0){
      const h8* src = hfrag + (size_t)(bwd ? t+1 : t-1)*3200 + dirOff + l;
      v4i w[7];
      for(;;){
        #pragma unroll
        for(int i=0;i<7;++i){
          unsigned long long ad = (unsigned long long)(src + (qb+i)*64);
          asm volatile("global_load_dwordx4 %0, %1, off sc1"
                       : "=v"(w[i]) : "v"(ad) : "memory");
        }
        // waitcnt with all 7 results tied: orders every subsequent read
        asm volatile("s_waitcnt vmcnt(0)"
          : "+v"(w[0]),"+v"(w[1]),"+v"(w[2]),"+v"(w[3]),"+v"(w[4]),
            "+v"(w[5]),"+v"(w[6])
          :
          : "memory");
        int orac = 0;
        #pragma unroll
        for(int i=0;i<7;++i) orac |= (w[i][0]|w[i][1]) | (w[i][2]|w[i][3]);
        if(__all((orac & 0x40004000) == 0)) break;
        __builtin_amdgcn_s_sleep(1);
      }
      // mirror clean chunks into LDS (byte-exact copy of the fragment region)
      #pragma unroll
      for(int i=0;i<7;++i)
        *(v4i*)(lbuf + (qb+i)*1024 + l*16) = w[i];
    }
    __syncthreads();

    // gates^T = Gp[t] + W_hh @ h_prev^T   (h fragments read from LDS as B)
    f4 acc[4];
    acc[0][0]=(float)gp4[0]; acc[0][1]=(float)gp4[1]; acc[0][2]=(float)gp4[2]; acc[0][3]=(float)gp4[3];
    #pragma unroll
    for(int j=1;j<4;++j){ acc[j][0]=0.f; acc[j][1]=0.f; acc[j][2]=0.f; acc[j][3]=0.f; }
    if(s > 0){
      #pragma unroll
      for(int q=0;q<KQ_HH;++q){
        v4i wq = *(const v4i*)(lbuf + q*1024 + l*16);
        acc[q&3] = __builtin_amdgcn_mfma_f32_16x16x32_f16(
                     Bf[q], __builtin_bit_cast(h8, wq), acc[q&3], 0,0,0);
      }
    }
    f4 g = (acc[0]+acc[1]) + (acc[2]+acc[3]);

    // per-lane cell: regs = i,f,g,o -- no shuffles, no redundancy
    float cn = sigmoidf_(g[1])*cs + sigmoidf_(g[0])*tanhf_(g[2]);
    cs = cn;
    float hv = sigmoidf_(g[3])*tanhf_(cn);

    // pack 4 units' f16 h per batch into 8B via 2 shfl_xor; lanes 0..15 store
    {
      _Float16 hf = (_Float16)hv;
      unsigned int u0 = (unsigned int)__builtin_bit_cast(unsigned short, hf);
      unsigned int up = (unsigned int)__shfl_xor((int)u0, 16, 64);
      unsigned int d01 = u0 | (up << 16);   // hi0 lanes: (u0,u1); hi2 lanes: (u2,u3)
      unsigned int d23 = (unsigned int)__shfl_xor((int)d01, 32, 64);
      if(l < 16){
        v2i ov; ov[0] = (int)d01; ov[1] = (int)d23;
        unsigned long long ad = (unsigned long long)
          ((char*)(hfrag + (size_t)t*3200 + dirOff + storeUnit + l) + storeHalf);
        asm volatile("global_store_dwordx2 %0, %1, off sc1" : : "v"(ad), "v"(ov) : "memory");
      }
    }
    // no vmcnt wait: next step's poll (or kernel end) drains the queue
  }
}

// ---------------- head: fc -> softmax-free atan2 -> SRF ---------------------
__global__ void head_kernel(const h8* __restrict__ h1f,
                            const float* __restrict__ fcw, const float* __restrict__ fcb,
                            const float* __restrict__ alphabet,
                            const float* __restrict__ bl, const float* __restrict__ ba,
                            float* __restrict__ srf)
{
  __shared__ h8 sh8[16*201];   // stride 201 units (3216B = 804 words, %32=4)
  __shared__ float slog[960];
  __shared__ float smax[16];
  __shared__ float sphi[48];
  const int t = blockIdx.x, tid = threadIdx.x;
  const h8* src = h1f + (size_t)t*3200;
  for(int u=tid; u<3200; u+=256){
    int q2 = u >> 6, r = u & 63, sub = r >> 4, m = r & 15;
    sh8[m*201 + (q2<<2) + sub] = src[u];
  }
  __syncthreads();
  for(int it=tid; it<960; it+=256){
    int j = it >> 4, b = it & 15;
    float acc = fcb[j];
    const float4* wr = (const float4*)(fcw + (size_t)j*1600);
    const h8* hr = sh8 + b*201;
    for(int k=0;k<200;++k){
      h8 hv = hr[k];
      float4 w0 = wr[2*k], w1 = wr[2*k+1];
      acc += w0.x*(float)hv[0] + w0.y*(float)hv[1] + w0.z*(float)hv[2] + w0.w*(float)hv[3]
           + w1.x*(float)hv[4] + w1.y*(float)hv[5] + w1.z*(float)hv[6] + w1.w*(float)hv[7];
    }
    slog[b*60 + j] = acc;
  }
  __syncthreads();
  if(tid < 16){
    float mx = -1e30f;
    for(int j=0;j<60;++j) mx = fmaxf(mx, slog[tid*60+j]);
    smax[tid] = mx;
  }
  __syncthreads();
  if(tid < 48){
    int b = tid/3, ax = tid%3;
    float s=0.f, c=0.f, mx = smax[b];
    for(int j=0;j<60;++j){
      float e = __expf(slog[b*60+j] - mx);
      float al = alphabet[j*3 + ax];
      s += e*__sinf(al); c += e*__cosf(al);
    }
    sphi[b*3+ax] = atan2f(s, c);   // softmax denominator cancels in atan2
  }
  __syncthreads();
  if(tid < 144){
    int jj = tid/48; int r_ = tid%48; int b = r_/3, ax = r_%3;
    float rr = bl[jj], th = ba[jj], ph = sphi[b*3+jj];
    float v = (ax==0) ? rr*__cosf(th)
            : (ax==1) ? rr*__cosf(ph)*__sinf(th)
                      : rr*__sinf(ph)*__sinf(th);
    srf[(((size_t)(3*t+jj))*16 + b)*3 + ax] = v;
  }
}

// ---------------- pNeRF: 384 chain scans + 23 fragment stitches -------------
__device__ __forceinline__ void frame_cols(
  float ax,float ay,float az, float bx,float by,float bz, float cx,float cy,float cz,
  float* R)
{
  float ux=cx-bx, uy=cy-by, uz=cz-bz;
  float ir = rsqrtf(ux*ux+uy*uy+uz*uz);
  float bcx=ux*ir, bcy=uy*ir, bcz=uz*ir;
  float px=bx-ax, py=by-ay, pz=bz-az;
  float nx=py*bcz-pz*bcy, ny=pz*bcx-px*bcz, nz=px*bcy-py*bcx;
  float in_ = rsqrtf(nx*nx+ny*ny+nz*nz);
  nx*=in_; ny*=in_; nz*=in_;
  float mx=ny*bcz-nz*bcy, my=nz*bcx-nx*bcz, mz=nx*bcy-ny*bcx;
  R[0]=bcx;R[1]=bcy;R[2]=bcz; R[3]=mx;R[4]=my;R[5]=mz; R[6]=nx;R[7]=ny;R[8]=nz;
}

__global__ void pnerf_kernel(const float* __restrict__ srf,
                             float* __restrict__ frag, float* __restrict__ out)
{
  __shared__ float tail[3][16][3];
  __shared__ float sR[16][9];
  __shared__ float sorg[16][3];
  const int tid = threadIdx.x;
  if(tid < 384){
    int k = tid >> 4, b = tid & 15;
    float ax=-0.70710678f, ay=1.22474487f, az=0.f;
    float bx=-1.41421356f, by=0.f, bz=0.f;
    float cx=0.f, cy=0.f, cz=0.f;
    for(int f=0; f<72; ++f){
      const float* ct = srf + (((size_t)(k*72+f))*16 + b)*3;
      float t0=ct[0], t1=ct[1], t2=ct[2];
      float R[9];
      frame_cols(ax,ay,az, bx,by,bz, cx,cy,cz, R);
      float dx = cx + R[0]*t0 + R[3]*t1 + R[6]*t2;
      float dy = cy + R[1]*t0 + R[4]*t1 + R[7]*t2;
      float dz = cz + R[2]*t0 + R[5]*t1 + R[8]*t2;
      float* fr = frag + (((size_t)(f*24+k))*16 + b)*3;
      fr[0]=dx; fr[1]=dy; fr[2]=dz;
      if(k == 0){
        float* o = out + ((size_t)(f*16)+b)*3;
        o[0]=dx; o[1]=dy; o[2]=dz;
        if(f >= 69){ tail[f-69][b][0]=dx; tail[f-69][b][1]=dy; tail[f-69][b][2]=dz; }
      }
      ax=bx; ay=by; az=bz;  bx=cx; by=cy; bz=cz;  cx=dx; cy=dy; cz=dz;
    }
  }
  __syncthreads();
  for(int kk=1; kk<24; ++kk){
    if(tid < 16){
      int b = tid;
      frame_cols(tail[0][b][0],tail[0][b][1],tail[0][b][2],
                 tail[1][b][0],tail[1][b][1],tail[1][b][2],
                 tail[2][b][0],tail[2][b][1],tail[2][b][2], &sR[b][0]);
      sorg[b][0]=tail[2][b][0]; sorg[b][1]=tail[2][b][1]; sorg[b][2]=tail[2][b][2];
    }
    __syncthreads();
    for(int idx=tid; idx<1152; idx+=blockDim.x){
      int f = idx >> 4, b = idx & 15;
      const float* v = frag + (((size_t)(f*24+kk))*16 + b)*3;
      float vx=v[0], vy=v[1], vz=v[2];
      float gx = sorg[b][0] + sR[b][0]*vx + sR[b][3]*vy + sR[b][6]*vz;
      float gy = sorg[b][1] + sR[b][1]*vx + sR[b][4]*vy + sR[b][7]*vz;
      float gz = sorg[b][2] + sR[b][2]*vx + sR[b][5]*vy + sR[b][8]*vz;
      float* o = out + (((size_t)(kk*72+f))*16 + b)*3;
      o[0]=gx; o[1]=gy; o[2]=gz;
      if(f >= 69){ tail[f-69][b][0]=gx; tail[f-69][b][1]=gy; tail[f-69][b][2]=gz; }
    }
    __syncthreads();
  }
}

// ---------------------------------------------------------------------------
extern "C" void kernel_launch(void* const* d_in, const int* in_sizes, int n_in,
                              void* d_out, int out_size, void* d_ws, size_t ws_size,
                              hipStream_t stream)
{
  (void)in_sizes; (void)n_in; (void)out_size; (void)ws_size;
  const int*   seq  = (const int*)d_in[0];
  const float* pssm = (const float*)d_in[1];
  const float* w_ih_l0f=(const float*)d_in[3];  const float* w_hh_l0f=(const float*)d_in[4];
  const float* b_ih_l0f=(const float*)d_in[5];  const float* b_hh_l0f=(const float*)d_in[6];
  const float* w_ih_l0b=(const float*)d_in[7];  const float* w_hh_l0b=(const float*)d_in[8];
  const float* b_ih_l0b=(const float*)d_in[9];  const float* b_hh_l0b=(const float*)d_in[10];
  const float* w_ih_l1f=(const float*)d_in[11]; const float* w_hh_l1f=(const float*)d_in[12];
  const float* b_ih_l1f=(const float*)d_in[13]; const float* b_hh_l1f=(const float*)d_in[14];
  const float* w_ih_l1b=(const float*)d_in[15]; const float* w_hh_l1b=(const float*)d_in[16];
  const float* b_ih_l1b=(const float*)d_in[17]; const float* b_hh_l1b=(const float*)d_in[18];
  const float* fc_w=(const float*)d_in[19];     const float* fc_b=(const float*)d_in[20];
  const float* alphabet=(const float*)d_in[21];
  const float* bl=(const float*)d_in[22];       const float* ba=(const float*)d_in[23];
  float* out = (float*)d_out;

  char* ws = (char*)d_ws;
  size_t o = 0;
  auto alloc = [&](size_t bytes){ size_t r = o; o = (o + bytes + 255) & ~(size_t)255; return r; };
  size_t o_wphh = alloc(4ull*320000*16);   // 20.48 MB  W_hh frags (4 dirs)
  size_t o_wp1  = alloc(2ull*640000*16);   // 20.48 MB  W_ih_l1 frags
  size_t o_wp0  = alloc(2ull*25600*16);    //  0.82 MB  W_ih_l0 frags (padded K=64)
  size_t o_gpf  = alloc(2ull*29491200);    // 58.98 MB  Gp fwd
  size_t o_gpb  = alloc(2ull*29491200);    // 58.98 MB  Gp bwd
  size_t o_h0   = alloc(16ull*576*3200);   // 29.49 MB  h0 frag layout (h8 units)
  size_t o_h1   = alloc(16ull*576*3200);   // 29.49 MB  h1 frag layout (contiguous after h0)
  size_t o_x    = alloc(2ull*589824);      //  1.18 MB  x f16 (9216,64)
  size_t o_srf  = alloc(4ull*82944);       //  SRF
  size_t o_frag = alloc(4ull*82944);       //  pnerf fragments

  h8* wp_hh = (h8*)(ws + o_wphh);
  h8* wp1   = (h8*)(ws + o_wp1);
  h8* wp0   = (h8*)(ws + o_wp0);
  _Float16* gpf = (_Float16*)(ws + o_gpf);
  _Float16* gpb = (_Float16*)(ws + o_gpb);
  h8* h0    = (h8*)(ws + o_h0);
  h8* h1    = (h8*)(ws + o_h1);
  _Float16* x = (_Float16*)(ws + o_x);
  float* srf    = (float*)(ws + o_srf);
  float* frag   = (float*)(ws + o_frag);

  // sentinel-init h0+h1 (contiguous: 2 x 576 x 3200 h8 = 3,686,400 v4i)
  init_h<<<14400, 256, 0, stream>>>((v4i*)(ws + o_h0));
  build_x<<<2304, 256, 0, stream>>>(seq, pssm, x);
  prep_w<<<10200, 256, 0, stream>>>(w_hh_l0f, w_hh_l0b, w_hh_l1f, w_hh_l1b,
                                    w_ih_l1f, w_ih_l1b, w_ih_l0f, w_ih_l0b,
                                    wp_hh, wp1, wp0);
  // layer 0 input projection
  gemm_l0<<<14400, 256, 0, stream>>>(x, wp0, wp0 + 25600,
                                     b_ih_l0f, b_hh_l0f, b_ih_l0b, b_hh_l0b, gpf, gpb);
  // layer 0 recurrence (round-6 winner: 100 blocks, 1 tile/wave)
  lstm_kernel<<<100, 256, 0, stream>>>(wp_hh, wp_hh + 320000, gpf, gpb, h0);
  // layer 1 input projection (M16/T8 tile + XCD-affinity swizzle, 2000 x 512)
  gemm_l1<<<2000, 512, 0, stream>>>(h0, wp1, wp1 + 640000,
                                    b_ih_l1f, b_hh_l1f, b_ih_l1b, b_hh_l1b, gpf, gpb);
  // layer 1 recurrence
  lstm_kernel<<<100, 256, 0, stream>>>(wp_hh + 640000, wp_hh + 960000, gpf, gpb, h1);
  // fc head -> torsions -> SRF
  head_kernel<<<576, 256, 0, stream>>>(h1, fc_w, fc_b, alphabet, bl, ba, srf);
  // geometric chain
  pnerf_kernel<<<1, 512, 0, stream>>>(srf, frag, out);
}

// Round 13
// 2716.984 us; speedup vs baseline: 1.0333x; 1.0333x over previous
//
#include <hip/hip_runtime.h>
#include <hip/hip_fp16.h>

// Problem constants
#define L_SEQ 576
#define BATCH 16
#define HIDDEN 800
#define NT 200      // N tiles per direction (3200/16)
#define KQ_HH 25    // K chunks for W_hh (800/32)
#define KQ_L1 50    // 1600/32
#define KQ_L0 2     // padded 64/32

typedef _Float16 h8 __attribute__((ext_vector_type(8)));
typedef _Float16 h4 __attribute__((ext_vector_type(4)));
typedef float f4 __attribute__((ext_vector_type(4)));
typedef int v4i __attribute__((ext_vector_type(4)));
typedef int v2i __attribute__((ext_vector_type(2)));

__device__ __forceinline__ float sigmoidf_(float x){
  x = fminf(30.f, fmaxf(-30.f, x));
  return 1.f/(1.f+__expf(-x));
}
__device__ __forceinline__ float tanhf_(float x){
  x = fminf(15.f, fmaxf(-15.f, x));
  float e = __expf(2.f*x);
  return (e-1.f)/(e+1.f);
}

// ---------------- init: fill region with f16 sentinel 0x7C00 (+Inf) ---------
// Dual-purpose sentinel: bit14=1 (h protocol: real |h|<1 -> bit14==0) AND
// exp-all-ones (Gp protocol: real |gate| <~200 << 65504 -> never Inf/NaN).
__global__ void init_h(v4i* __restrict__ h){
  size_t i = (size_t)blockIdx.x*256 + threadIdx.x;
  v4i s = {0x7C007C00, 0x7C007C00, 0x7C007C00, 0x7C007C00};
  h[i] = s;
}

// ---------------- build x (L*B, 64) f16: [onehot(20) | pssm(21) | pad0] -----
__global__ void build_x(const int* __restrict__ seq, const float* __restrict__ pssm,
                        _Float16* __restrict__ x){
  int i = blockIdx.x*256 + threadIdx.x;
  if(i >= L_SEQ*BATCH*64) return;
  int m = i >> 6, k = i & 63;
  float v = 0.f;
  if(k < 20)      v = (seq[m]==k) ? 1.f : 0.f;
  else if(k < 41) v = pssm[m*21 + (k-20)];
  x[i] = (_Float16)v;
}

// ---------------- weight prep: fp32 -> f16 MFMA fragment layout --------------
// Fragments consumed as the A-operand (W on the M-side) of the transposed
// MFMA. A-frag(M) and B-frag(M^T) are byte-identical on mfma_f32_16x16x32_f16
// (lane l -> primary dim l&15, k-run (l>>4)*8+j) -- unchanged from the
// validated round-2 version.
__global__ void prep_w(
  const float* __restrict__ whh0f, const float* __restrict__ whh0b,
  const float* __restrict__ whh1f, const float* __restrict__ whh1b,
  const float* __restrict__ wih1f, const float* __restrict__ wih1b,
  const float* __restrict__ wih0f, const float* __restrict__ wih0b,
  h8* __restrict__ wp_hh, h8* __restrict__ wp1, h8* __restrict__ wp0)
{
  long idx = (long)blockIdx.x*256 + threadIdx.x;
  const long J1 = 4L*320000, J2 = 2L*640000, J3 = 2L*25600;
  if(idx < J1){
    int d = (int)(idx/320000); int r = (int)(idx%320000);
    int T = r/1600, q = (r%1600)/64, l = r&63;
    const float* W = (d==0)?whh0f:(d==1)?whh0b:(d==2)?whh1f:whh1b;
    int c = l&15; int n = (c&3)*800 + T*4 + (c>>2);
    const float* src = W + (size_t)n*800 + q*32 + ((l>>4)<<3);
    h8 v;
    #pragma unroll
    for(int j=0;j<8;++j) v[j] = (_Float16)src[j];
    wp_hh[idx] = v;
  } else if(idx < J1+J2){
    long i2 = idx - J1;
    int d = (int)(i2/640000); int r = (int)(i2%640000);
    int T = r/3200, q = (r%3200)/64, l = r&63;
    const float* W = d ? wih1b : wih1f;
    int c = l&15; int n = (c&3)*800 + T*4 + (c>>2);
    const float* src = W + (size_t)n*1600 + q*32 + ((l>>4)<<3);
    h8 v;
    #pragma unroll
    for(int j=0;j<8;++j) v[j] = (_Float16)src[j];
    wp1[i2] = v;
  } else if(idx < J1+J2+J3){
    long i3 = idx - J1 - J2;
    int d = (int)(i3/25600); int r = (int)(i3%25600);
    int T = r/128, q = (r%128)/64, l = r&63;
    const float* W = d ? wih0b : wih0f;
    int c = l&15; int n = (c&3)*800 + T*4 + (c>>2);
    int k0 = q*32 + ((l>>4)<<3);
    h8 v;
    #pragma unroll
    for(int j=0;j<8;++j){ int k = k0+j; v[j] = (_Float16)((k<41)? W[(size_t)n*41+k] : 0.f); }
    wp0[i3] = v;
  }
}

// ------------- layer-0 input projection, TRANSPOSED (gates^T = W @ x^T) -----
__global__ __launch_bounds__(256) void gemm_l0(
  const _Float16* __restrict__ A,
  const h8* __restrict__ WpF, const h8* __restrict__ WpB,
  const float* __restrict__ bihF, const float* __restrict__ bhhF,
  const float* __restrict__ bihB, const float* __restrict__ bhhB,
  _Float16* __restrict__ GpF, _Float16* __restrict__ GpB)
{
  const int wv = threadIdx.x >> 6;
  const int l  = threadIdx.x & 63;
  const int mg = blockIdx.x % 144;
  const int tg = blockIdx.x / 144;       // 0..99
  const int mt = mg*4 + wv;              // 0..575 (timestep)
  const int dir = tg / 50;
  const int Tb  = (tg % 50) * 4;
  const h8* Wp = dir ? WpB : WpF;
  const float* bih = dir ? bihB : bihF;
  const float* bhh = dir ? bhhB : bhhF;
  _Float16* Gp = dir ? GpB : GpF;

  const _Float16* ab = A + (size_t)(mt*16 + (l&15))*64 + ((l>>4)<<3);
  f4 acc[4] = {{0.f,0.f,0.f,0.f},{0.f,0.f,0.f,0.f},{0.f,0.f,0.f,0.f},{0.f,0.f,0.f,0.f}};
  for(int q=0;q<KQ_L0;++q){
    h8 av = *(const h8*)(ab + q*32);
    #pragma unroll
    for(int j=0;j<4;++j){
      h8 bv = Wp[((size_t)(Tb+j)*KQ_L0 + q)*64 + l];
      acc[j] = __builtin_amdgcn_mfma_f32_16x16x32_f16(bv, av, acc[j], 0, 0, 0);
    }
  }
  const int hi = l >> 4;
  #pragma unroll
  for(int j=0;j<4;++j){
    int T = Tb + j;
    int u = T*4 + hi;
    h4 o;
    #pragma unroll
    for(int r=0;r<4;++r){
      float bias = bih[r*800+u] + bhh[r*800+u];
      o[r] = (_Float16)(acc[j][r] + bias);
    }
    *(h4*)(Gp + (((size_t)mt*NT + T)*64 + l)*4) = o;
  }
}

// ---------------- persistent LSTM layer (sentinel-sync, flag-free) -----------
// ROUND-6 WINNER, verbatim -- used for LAYER 0 only now (layer 1 is fused).
// DO NOT re-attempt: (a) bottom-of-loop pipelined sweep issue (round-3 raced
// on HW); (b) 2-tiles-per-wave consolidation (round-7, +27%).
__global__ __launch_bounds__(256,1) void lstm_kernel(
  const h8* __restrict__ WpF, const h8* __restrict__ WpB,
  const _Float16* __restrict__ GpF, const _Float16* __restrict__ GpB,
  h8* __restrict__ hfrag)
{
  __shared__ __attribute__((aligned(16))) char lds_h[2*25600];
  const int tid = threadIdx.x;
  const int wv  = tid >> 6;
  const int l   = tid & 63;
  const bool bwd = blockIdx.x >= 50;
  const int T = ((bwd ? (int)blockIdx.x - 50 : (int)blockIdx.x) << 2) + wv;  // 0..199
  const h8* Wp = bwd ? WpB : WpF;
  const _Float16* Gp = bwd ? GpB : GpF;
  const int dirOff = bwd ? 1600 : 0;     // h8 units

  h8 Bf[KQ_HH];
  #pragma unroll
  for(int q=0;q<KQ_HH;++q) Bf[q] = Wp[(T*KQ_HH + q)*64 + l];

  float cs = 0.f;                        // one cell per lane
  const int qb = wv*6;                   // this wave's poll base chunk
  const int storeUnit = ((T>>3)<<6) + (((T>>1)&3)<<4);  // h8-unit offset (+b)
  const int storeHalf = (T&1)<<3;                        // byte offset

  for(int s=0; s<L_SEQ; ++s){
    const int t = bwd ? (L_SEQ-1-s) : s;

    // prefetch Gp[t] (plain cached): 4 gates of this lane's cell
    h4 gp4 = *(const h4*)(Gp + (((size_t)t*NT + T)*64 + l)*4);

    #pragma unroll
    for(int q=0;q<KQ_HH;++q) asm volatile("" : "+v"(Bf[q]));   // keep resident

    char* lbuf = lds_h + (s&1)*25600;
    if(s > 0){
      const h8* src = hfrag + (size_t)(bwd ? t+1 : t-1)*3200 + dirOff + l;
      v4i w[7];
      for(;;){
        #pragma unroll
        for(int i=0;i<7;++i){
          unsigned long long ad = (unsigned long long)(src + (qb+i)*64);
          asm volatile("global_load_dwordx4 %0, %1, off sc1"
                       : "=v"(w[i]) : "v"(ad) : "memory");
        }
        asm volatile("s_waitcnt vmcnt(0)"
          : "+v"(w[0]),"+v"(w[1]),"+v"(w[2]),"+v"(w[3]),"+v"(w[4]),
            "+v"(w[5]),"+v"(w[6])
          :
          : "memory");
        int orac = 0;
        #pragma unroll
        for(int i=0;i<7;++i) orac |= (w[i][0]|w[i][1]) | (w[i][2]|w[i][3]);
        if(__all((orac & 0x40004000) == 0)) break;
        __builtin_amdgcn_s_sleep(1);
      }
      #pragma unroll
      for(int i=0;i<7;++i)
        *(v4i*)(lbuf + (qb+i)*1024 + l*16) = w[i];
    }
    __syncthreads();

    f4 acc[4];
    acc[0][0]=(float)gp4[0]; acc[0][1]=(float)gp4[1]; acc[0][2]=(float)gp4[2]; acc[0][3]=(float)gp4[3];
    #pragma unroll
    for(int j=1;j<4;++j){ acc[j][0]=0.f; acc[j][1]=0.f; acc[j][2]=0.f; acc[j][3]=0.f; }
    if(s > 0){
      #pragma unroll
      for(int q=0;q<KQ_HH;++q){
        v4i wq = *(const v4i*)(lbuf + q*1024 + l*16);
        acc[q&3] = __builtin_amdgcn_mfma_f32_16x16x32_f16(
                     Bf[q], __builtin_bit_cast(h8, wq), acc[q&3], 0,0,0);
      }
    }
    f4 g = (acc[0]+acc[1]) + (acc[2]+acc[3]);

    float cn = sigmoidf_(g[1])*cs + sigmoidf_(g[0])*tanhf_(g[2]);
    cs = cn;
    float hv = sigmoidf_(g[3])*tanhf_(cn);

    {
      _Float16 hf = (_Float16)hv;
      unsigned int u0 = (unsigned int)__builtin_bit_cast(unsigned short, hf);
      unsigned int up = (unsigned int)__shfl_xor((int)u0, 16, 64);
      unsigned int d01 = u0 | (up << 16);
      unsigned int d23 = (unsigned int)__shfl_xor((int)d01, 32, 64);
      if(l < 16){
        v2i ov; ov[0] = (int)d01; ov[1] = (int)d23;
        unsigned long long ad = (unsigned long long)
          ((char*)(hfrag + (size_t)t*3200 + dirOff + storeUnit + l) + storeHalf);
        asm volatile("global_store_dwordx2 %0, %1, off sc1" : : "v"(ad), "v"(ov) : "memory");
      }
    }
  }
}

// ---------------- FUSED layer-1: gemm_l1 + lstm1 in one launch ---------------
// ROUND-12. Timeline was lstm0(1085) -> gemm_l1(400, serialized, 156 CUs idle
// during lstm) -> lstm1(1085). Layer-1 consumes Gp[t] at ~1.9us/step while
// gemm produces a 16-step Gp panel in ~11-17us -> production stays ahead if
// concurrent. Fusion: blocks 0..99 = lstm role (round-6 body, 256 of 512
// threads active, idle waves only hit the per-step barrier); blocks 100..2099
// = gemm role (round-11 tile, sc1 stores), ordered fwd-mg-ascending /
// bwd-mg-descending so earliest-needed panels are produced first.
// Sync: Gp is sentinel-inited to 0x7C00 (+Inf) after lstm0. Real gate
// pre-activations are bounded (|g|<~200 << 65504) so exp-all-ones NEVER
// occurs in real data -> data-as-signal poll on Gp with (x&0x7C00)==0x7C00,
// same issue->vmcnt-tied->check->sleep->reissue idiom as the h poll. The Gp
// sc1 load is issued BEFORE the h poll (both latencies overlap); issue and
// wait are within the same loop iteration (unlike the round-3 cross-back-edge
// variant that raced). All Gp access inside this kernel is sc1 (no kernel
// boundary -> plain loads could see stale L2).
// Liveness: gemm blocks poll nothing (h0 complete) -> always progress; >=156
// CUs run gemm; lstm Gp polls eventually satisfied. No deadlock.
__global__ __launch_bounds__(512,1) void fused_l1(
  const h8* __restrict__ WhF, const h8* __restrict__ WhB,   // W_hh l1 frags
  _Float16* __restrict__ GpF, _Float16* __restrict__ GpB,   // l1 gates (sentinel)
  h8* __restrict__ hfrag,                                   // h1 out
  const h8* __restrict__ Af,                                // h0 (complete)
  const h8* __restrict__ W1F, const h8* __restrict__ W1B,   // W_ih l1 frags
  const float* __restrict__ bihF, const float* __restrict__ bhhF,
  const float* __restrict__ bihB, const float* __restrict__ bhhB)
{
  __shared__ __attribute__((aligned(16))) char smem[2*25600];
  const int tid = threadIdx.x;
  if(blockIdx.x < 100){
    // ------------------------- lstm role -------------------------
    const bool act = tid < 256;
    const int wv = (tid >> 6) & 3;
    const int l  = tid & 63;
    const bool bwd = blockIdx.x >= 50;
    const int T = ((bwd ? (int)blockIdx.x - 50 : (int)blockIdx.x) << 2) + wv;
    const h8* Wp = bwd ? WhB : WhF;
    const _Float16* Gp = bwd ? GpB : GpF;
    const int dirOff = bwd ? 1600 : 0;

    h8 Bf[KQ_HH];
    if(act){
      #pragma unroll
      for(int q=0;q<KQ_HH;++q) Bf[q] = Wp[(T*KQ_HH + q)*64 + l];
    }
    float cs = 0.f;
    const int qb = wv*6;
    const int storeUnit = ((T>>3)<<6) + (((T>>1)&3)<<4);
    const int storeHalf = (T&1)<<3;

    for(int s=0; s<L_SEQ; ++s){
      const int t = bwd ? (L_SEQ-1-s) : s;
      v2i gpw;
      char* lbuf = smem + (s&1)*25600;
      unsigned long long gpad = 0;
      if(act){
        gpad = (unsigned long long)(Gp + (((size_t)t*NT + T)*64 + l)*4);
        // issue Gp sc1 load; waits alongside the h poll
        asm volatile("global_load_dwordx2 %0, %1, off sc1"
                     : "=v"(gpw) : "v"(gpad) : "memory");
        #pragma unroll
        for(int q=0;q<KQ_HH;++q) asm volatile("" : "+v"(Bf[q]));
        if(s > 0){
          const h8* src = hfrag + (size_t)(bwd ? t+1 : t-1)*3200 + dirOff + l;
          v4i w[7];
          for(;;){
            #pragma unroll
            for(int i=0;i<7;++i){
              unsigned long long ad = (unsigned long long)(src + (qb+i)*64);
              asm volatile("global_load_dwordx4 %0, %1, off sc1"
                           : "=v"(w[i]) : "v"(ad) : "memory");
            }
            asm volatile("s_waitcnt vmcnt(0)"
              : "+v"(w[0]),"+v"(w[1]),"+v"(w[2]),"+v"(w[3]),"+v"(w[4]),
                "+v"(w[5]),"+v"(w[6])
              :
              : "memory");
            int orac = 0;
            #pragma unroll
            for(int i=0;i<7;++i) orac |= (w[i][0]|w[i][1]) | (w[i][2]|w[i][3]);
            if(__all((orac & 0x40004000) == 0)) break;
            __builtin_amdgcn_s_sleep(1);
          }
          #pragma unroll
          for(int i=0;i<7;++i)
            *(v4i*)(lbuf + (qb+i)*1024 + l*16) = w[i];
        }
      }
      __syncthreads();
      if(act){
        // Gp sentinel wait (usually immediate: producer stays ahead)
        for(;;){
          asm volatile("s_waitcnt vmcnt(0)" : "+v"(gpw) : : "memory");
          int lo = gpw[0], hi = gpw[1];
          int na = (((lo & 0x7C00) == 0x7C00) ? 1 : 0)
                 | ((((lo>>16) & 0x7C00) == 0x7C00) ? 1 : 0)
                 | (((hi & 0x7C00) == 0x7C00) ? 1 : 0)
                 | ((((hi>>16) & 0x7C00) == 0x7C00) ? 1 : 0);
          if(__all(na == 0)) break;
          __builtin_amdgcn_s_sleep(1);
          asm volatile("global_load_dwordx2 %0, %1, off sc1"
                       : "=v"(gpw) : "v"(gpad) : "memory");
        }
        h4 gp4 = __builtin_bit_cast(h4, gpw);

        f4 acc[4];
        acc[0][0]=(float)gp4[0]; acc[0][1]=(float)gp4[1]; acc[0][2]=(float)gp4[2]; acc[0][3]=(float)gp4[3];
        #pragma unroll
        for(int j=1;j<4;++j){ acc[j][0]=0.f; acc[j][1]=0.f; acc[j][2]=0.f; acc[j][3]=0.f; }
        if(s > 0){
          #pragma unroll
          for(int q=0;q<KQ_HH;++q){
            v4i wq = *(const v4i*)(lbuf + q*1024 + l*16);
            acc[q&3] = __builtin_amdgcn_mfma_f32_16x16x32_f16(
                         Bf[q], __builtin_bit_cast(h8, wq), acc[q&3], 0,0,0);
          }
        }
        f4 g = (acc[0]+acc[1]) + (acc[2]+acc[3]);

        float cn = sigmoidf_(g[1])*cs + sigmoidf_(g[0])*tanhf_(g[2]);
        cs = cn;
        float hv = sigmoidf_(g[3])*tanhf_(cn);

        _Float16 hf = (_Float16)hv;
        unsigned int u0 = (unsigned int)__builtin_bit_cast(unsigned short, hf);
        unsigned int up = (unsigned int)__shfl_xor((int)u0, 16, 64);
        unsigned int d01 = u0 | (up << 16);
        unsigned int d23 = (unsigned int)__shfl_xor((int)d01, 32, 64);
        if(l < 16){
          v2i ov; ov[0] = (int)d01; ov[1] = (int)d23;
          unsigned long long ad = (unsigned long long)
            ((char*)(hfrag + (size_t)t*3200 + dirOff + storeUnit + l) + storeHalf);
          asm volatile("global_store_dwordx2 %0, %1, off sc1" : : "v"(ad), "v"(ov) : "memory");
        }
      }
    }
  } else {
    // ------------------------- gemm role -------------------------
    v4i (*ldsW)[512] = (v4i(*)[512])smem;   // [2][512] = 16KB of the 50KB
    const int wv = tid >> 6;                // 0..7
    const int l  = tid & 63;
    const int g  = (int)blockIdx.x - 100;   // 0..1999
    const int dir = g & 1;
    const int p   = g >> 1;                 // 0..999
    const int mgs = p / 25;                 // 0..39 (>=36 invalid)
    const int tg  = p % 25;
    if(mgs >= 36) return;
    const int mg = dir ? (35 - mgs) : mgs;  // fwd ascending, bwd descending
    const int Tb = tg * 8;
    const int mt0 = mg*16 + wv*2;
    const h8* Wp = dir ? W1B : W1F;
    const float* bih = dir ? bihB : bihF;
    const float* bhh = dir ? bhhB : bhhF;
    _Float16* Gp = dir ? GpB : GpF;

    const h8* a0 = Af + (size_t)(mt0+0)*3200 + l;
    const h8* a1 = Af + (size_t)(mt0+1)*3200 + l;

    f4 acc[2][8];
    #pragma unroll
    for(int m=0;m<2;++m)
      #pragma unroll
      for(int j=0;j<8;++j){ acc[m][j][0]=0.f; acc[m][j][1]=0.f; acc[m][j][2]=0.f; acc[m][j][3]=0.f; }

    {
      int j = tid >> 6, ll = tid & 63;
      ldsW[0][tid] = *(const v4i*)(Wp + ((size_t)(Tb+j)*KQ_L1 + 0)*64 + ll);
    }
    h8 av0 = a0[0], av1 = a1[0];
    __syncthreads();
    for(int q=0;q<KQ_L1;++q){
      const int buf = q & 1;
      const int qn = (q+1 < KQ_L1) ? q+1 : q;
      if(q+1 < KQ_L1){
        int j = tid >> 6, ll = tid & 63;
        ldsW[buf^1][tid] = *(const v4i*)(Wp + ((size_t)(Tb+j)*KQ_L1 + (q+1))*64 + ll);
      }
      h8 an0 = a0[qn*64], an1 = a1[qn*64];
      #pragma unroll
      for(int j=0;j<8;++j){
        h8 bv = __builtin_bit_cast(h8, ldsW[buf][j*64 + l]);
        acc[0][j] = __builtin_amdgcn_mfma_f32_16x16x32_f16(bv, av0, acc[0][j], 0, 0, 0);
        acc[1][j] = __builtin_amdgcn_mfma_f32_16x16x32_f16(bv, av1, acc[1][j], 0, 0, 0);
      }
      __syncthreads();
      av0 = an0; av1 = an1;
    }
    const int hi = l >> 4;
    #pragma unroll
    for(int j=0;j<8;++j){
      int T = Tb + j;
      int u = T*4 + hi;
      float b0 = bih[0*800+u] + bhh[0*800+u];
      float b1 = bih[1*800+u] + bhh[1*800+u];
      float b2 = bih[2*800+u] + bhh[2*800+u];
      float b3 = bih[3*800+u] + bhh[3*800+u];
      #pragma unroll
      for(int m=0;m<2;++m){
        h4 o;
        o[0]=(_Float16)(acc[m][j][0]+b0); o[1]=(_Float16)(acc[m][j][1]+b1);
        o[2]=(_Float16)(acc[m][j][2]+b2); o[3]=(_Float16)(acc[m][j][3]+b3);
        v2i ov = __builtin_bit_cast(v2i, o);
        unsigned long long ad = (unsigned long long)
          (Gp + (((size_t)(mt0+m)*NT + T)*64 + l)*4);
        asm volatile("global_store_dwordx2 %0, %1, off sc1" : : "v"(ad), "v"(ov) : "memory");
      }
    }
  }
}

// ---------------- head: fc -> softmax-free atan2 -> SRF ---------------------
__global__ void head_kernel(const h8* __restrict__ h1f,
                            const float* __restrict__ fcw, const float* __restrict__ fcb,
                            const float* __restrict__ alphabet,
                            const float* __restrict__ bl, const float* __restrict__ ba,
                            float* __restrict__ srf)
{
  __shared__ h8 sh8[16*201];   // stride 201 units (3216B = 804 words, %32=4)
  __shared__ float slog[960];
  __shared__ float smax[16];
  __shared__ float sphi[48];
  const int t = blockIdx.x, tid = threadIdx.x;
  const h8* src = h1f + (size_t)t*3200;
  for(int u=tid; u<3200; u+=256){
    int q2 = u >> 6, r = u & 63, sub = r >> 4, m = r & 15;
    sh8[m*201 + (q2<<2) + sub] = src[u];
  }
  __syncthreads();
  for(int it=tid; it<960; it+=256){
    int j = it >> 4, b = it & 15;
    float acc = fcb[j];
    const float4* wr = (const float4*)(fcw + (size_t)j*1600);
    const h8* hr = sh8 + b*201;
    for(int k=0;k<200;++k){
      h8 hv = hr[k];
      float4 w0 = wr[2*k], w1 = wr[2*k+1];
      acc += w0.x*(float)hv[0] + w0.y*(float)hv[1] + w0.z*(float)hv[2] + w0.w*(float)hv[3]
           + w1.x*(float)hv[4] + w1.y*(float)hv[5] + w1.z*(float)hv[6] + w1.w*(float)hv[7];
    }
    slog[b*60 + j] = acc;
  }
  __syncthreads();
  if(tid < 16){
    float mx = -1e30f;
    for(int j=0;j<60;++j) mx = fmaxf(mx, slog[tid*60+j]);
    smax[tid] = mx;
  }
  __syncthreads();
  if(tid < 48){
    int b = tid/3, ax = tid%3;
    float s=0.f, c=0.f, mx = smax[b];
    for(int j=0;j<60;++j){
      float e = __expf(slog[b*60+j] - mx);
      float al = alphabet[j*3 + ax];
      s += e*__sinf(al); c += e*__cosf(al);
    }
    sphi[b*3+ax] = atan2f(s, c);   // softmax denominator cancels in atan2
  }
  __syncthreads();
  if(tid < 144){
    int jj = tid/48; int r_ = tid%48; int b = r_/3, ax = r_%3;
    float rr = bl[jj], th = ba[jj], ph = sphi[b*3+jj];
    float v = (ax==0) ? rr*__cosf(th)
            : (ax==1) ? rr*__cosf(ph)*__sinf(th)
                      : rr*__sinf(ph)*__sinf(th);
    srf[(((size_t)(3*t+jj))*16 + b)*3 + ax] = v;
  }
}

// ---------------- pNeRF: 384 chain scans + 23 fragment stitches -------------
__device__ __forceinline__ void frame_cols(
  float ax,float ay,float az, float bx,float by,float bz, float cx,float cy,float cz,
  float* R)
{
  float ux=cx-bx, uy=cy-by, uz=cz-bz;
  float ir = rsqrtf(ux*ux+uy*uy+uz*uz);
  float bcx=ux*ir, bcy=uy*ir, bcz=uz*ir;
  float px=bx-ax, py=by-ay, pz=bz-az;
  float nx=py*bcz-pz*bcy, ny=pz*bcx-px*bcz, nz=px*bcy-py*bcx;
  float in_ = rsqrtf(nx*nx+ny*ny+nz*nz);
  nx*=in_; ny*=in_; nz*=in_;
  float mx=ny*bcz-nz*bcy, my=nz*bcx-nx*bcz, mz=nx*bcy-ny*bcx;
  R[0]=bcx;R[1]=bcy;R[2]=bcz; R[3]=mx;R[4]=my;R[5]=mz; R[6]=nx;R[7]=ny;R[8]=nz;
}

__global__ void pnerf_kernel(const float* __restrict__ srf,
                             float* __restrict__ frag, float* __restrict__ out)
{
  __shared__ float tail[3][16][3];
  __shared__ float sR[16][9];
  __shared__ float sorg[16][3];
  const int tid = threadIdx.x;
  if(tid < 384){
    int k = tid >> 4, b = tid & 15;
    float ax=-0.70710678f, ay=1.22474487f, az=0.f;
    float bx=-1.41421356f, by=0.f, bz=0.f;
    float cx=0.f, cy=0.f, cz=0.f;
    for(int f=0; f<72; ++f){
      const float* ct = srf + (((size_t)(k*72+f))*16 + b)*3;
      float t0=ct[0], t1=ct[1], t2=ct[2];
      float R[9];
      frame_cols(ax,ay,az, bx,by,bz, cx,cy,cz, R);
      float dx = cx + R[0]*t0 + R[3]*t1 + R[6]*t2;
      float dy = cy + R[1]*t0 + R[4]*t1 + R[7]*t2;
      float dz = cz + R[2]*t0 + R[5]*t1 + R[8]*t2;
      float* fr = frag + (((size_t)(f*24+k))*16 + b)*3;
      fr[0]=dx; fr[1]=dy; fr[2]=dz;
      if(k == 0){
        float* o = out + ((size_t)(f*16)+b)*3;
        o[0]=dx; o[1]=dy; o[2]=dz;
        if(f >= 69){ tail[f-69][b][0]=dx; tail[f-69][b][1]=dy; tail[f-69][b][2]=dz; }
      }
      ax=bx; ay=by; az=bz;  bx=cx; by=cy; bz=cz;  cx=dx; cy=dy; cz=dz;
    }
  }
  __syncthreads();
  for(int kk=1; kk<24; ++kk){
    if(tid < 16){
      int b = tid;
      frame_cols(tail[0][b][0],tail[0][b][1],tail[0][b][2],
                 tail[1][b][0],tail[1][b][1],tail[1][b][2],
                 tail[2][b][0],tail[2][b][1],tail[2][b][2], &sR[b][0]);
      sorg[b][0]=tail[2][b][0]; sorg[b][1]=tail[2][b][1]; sorg[b][2]=tail[2][b][2];
    }
    __syncthreads();
    for(int idx=tid; idx<1152; idx+=blockDim.x){
      int f = idx >> 4, b = idx & 15;
      const float* v = frag + (((size_t)(f*24+kk))*16 + b)*3;
      float vx=v[0], vy=v[1], vz=v[2];
      float gx = sorg[b][0] + sR[b][0]*vx + sR[b][3]*vy + sR[b][6]*vz;
      float gy = sorg[b][1] + sR[b][1]*vx + sR[b][4]*vy + sR[b][7]*vz;
      float gz = sorg[b][2] + sR[b][2]*vx + sR[b][5]*vy + sR[b][8]*vz;
      float* o = out + (((size_t)(kk*72+f))*16 + b)*3;
      o[0]=gx; o[1]=gy; o[2]=gz;
      if(f >= 69){ tail[f-69][b][0]=gx; tail[f-69][b][1]=gy; tail[f-69][b][2]=gz; }
    }
    __syncthreads();
  }
}

// ---------------------------------------------------------------------------
extern "C" void kernel_launch(void* const* d_in, const int* in_sizes, int n_in,
                              void* d_out, int out_size, void* d_ws, size_t ws_size,
                              hipStream_t stream)
{
  (void)in_sizes; (void)n_in; (void)out_size; (void)ws_size;
  const int*   seq  = (const int*)d_in[0];
  const float* pssm = (const float*)d_in[1];
  const float* w_ih_l0f=(const float*)d_in[3];  const float* w_hh_l0f=(const float*)d_in[4];
  const float* b_ih_l0f=(const float*)d_in[5];  const float* b_hh_l0f=(const float*)d_in[6];
  const float* w_ih_l0b=(const float*)d_in[7];  const float* w_hh_l0b=(const float*)d_in[8];
  const float* b_ih_l0b=(const float*)d_in[9];  const float* b_hh_l0b=(const float*)d_in[10];
  const float* w_ih_l1f=(const float*)d_in[11]; const float* w_hh_l1f=(const float*)d_in[12];
  const float* b_ih_l1f=(const float*)d_in[13]; const float* b_hh_l1f=(const float*)d_in[14];
  const float* w_ih_l1b=(const float*)d_in[15]; const float* w_hh_l1b=(const float*)d_in[16];
  const float* b_ih_l1b=(const float*)d_in[17]; const float* b_hh_l1b=(const float*)d_in[18];
  const float* fc_w=(const float*)d_in[19];     const float* fc_b=(const float*)d_in[20];
  const float* alphabet=(const float*)d_in[21];
  const float* bl=(const float*)d_in[22];       const float* ba=(const float*)d_in[23];
  float* out = (float*)d_out;

  char* ws = (char*)d_ws;
  size_t o = 0;
  auto alloc = [&](size_t bytes){ size_t r = o; o = (o + bytes + 255) & ~(size_t)255; return r; };
  size_t o_wphh = alloc(4ull*320000*16);   // 20.48 MB  W_hh frags (4 dirs)
  size_t o_wp1  = alloc(2ull*640000*16);   // 20.48 MB  W_ih_l1 frags
  size_t o_wp0  = alloc(2ull*25600*16);    //  0.82 MB  W_ih_l0 frags (padded K=64)
  size_t o_gpf  = alloc(2ull*29491200);    // 58.98 MB  Gp fwd
  size_t o_gpb  = alloc(2ull*29491200);    // 58.98 MB  Gp bwd (contiguous after gpf)
  size_t o_h0   = alloc(16ull*576*3200);   // 29.49 MB  h0 frag layout (h8 units)
  size_t o_h1   = alloc(16ull*576*3200);   // 29.49 MB  h1 frag layout (contiguous after h0)
  size_t o_x    = alloc(2ull*589824);      //  1.18 MB  x f16 (9216,64)
  size_t o_srf  = alloc(4ull*82944);       //  SRF
  size_t o_frag = alloc(4ull*82944);       //  pnerf fragments

  h8* wp_hh = (h8*)(ws + o_wphh);
  h8* wp1   = (h8*)(ws + o_wp1);
  h8* wp0   = (h8*)(ws + o_wp0);
  _Float16* gpf = (_Float16*)(ws + o_gpf);
  _Float16* gpb = (_Float16*)(ws + o_gpb);
  h8* h0    = (h8*)(ws + o_h0);
  h8* h1    = (h8*)(ws + o_h1);
  _Float16* x = (_Float16*)(ws + o_x);
  float* srf    = (float*)(ws + o_srf);
  float* frag   = (float*)(ws + o_frag);

  // sentinel-init h0+h1 (contiguous: 2 x 576 x 3200 h8 = 3,686,400 v4i)
  init_h<<<14400, 256, 0, stream>>>((v4i*)(ws + o_h0));
  build_x<<<2304, 256, 0, stream>>>(seq, pssm, x);
  prep_w<<<10200, 256, 0, stream>>>(w_hh_l0f, w_hh_l0b, w_hh_l1f, w_hh_l1b,
                                    w_ih_l1f, w_ih_l1b, w_ih_l0f, w_ih_l0b,
                                    wp_hh, wp1, wp0);
  // layer 0 input projection
  gemm_l0<<<14400, 256, 0, stream>>>(x, wp0, wp0 + 25600,
                                     b_ih_l0f, b_hh_l0f, b_ih_l0b, b_hh_l0b, gpf, gpb);
  // layer 0 recurrence (round-6 winner: 100 blocks, 1 tile/wave)
  lstm_kernel<<<100, 256, 0, stream>>>(wp_hh, wp_hh + 320000, gpf, gpb, h0);
  // re-sentinel Gp (gpf+gpb contiguous: 117,964,800 B = 7,372,800 v4i)
  init_h<<<28800, 256, 0, stream>>>((v4i*)(ws + o_gpf));
  // FUSED layer-1: gemm role (2000 blocks) + lstm role (100 blocks)
  fused_l1<<<2100, 512, 0, stream>>>(wp_hh + 640000, wp_hh + 960000,
                                     gpf, gpb, h1, h0,
                                     wp1, wp1 + 640000,
                                     b_ih_l1f, b_hh_l1f, b_ih_l1b, b_hh_l1b);
  // fc head -> torsions -> SRF
  head_kernel<<<576, 256, 0, stream>>>(h1, fc_w, fc_b, alphabet, bl, ba, srf);
  // geometric chain
  pnerf_kernel<<<1, 512, 0, stream>>>(srf, frag, out);
}